// Round 3
// baseline (49.464 us; speedup 1.0000x reference)
//
#include <hip/hip_runtime.h>
#include <math.h>

// Problem constants (compile-time; from reference setup_inputs)
#define BATCH     65536
#define NNBR      8
#define DIM       16
#define HALF_L2W  5.0e-5f          // 0.5 * L2_WEIGHT

#define GRID      1024
#define BLOCK     256
#define NTH       (GRID * BLOCK)   // 262144 threads, 4 blocks/CU co-resident
#define ROWS_PB   64               // BLOCK / 4 lanes-per-row

// table sizes in float4 units (hardcoded so streaming loops fully unroll)
#define N_E4      8000000          // 2,000,000 * 16 / 4
#define N_U4      400000           // 100,000 * 16 / 4
#define N_R4      256              // 64 * 16 / 4

#define E_ITERS   (N_E4 / NTH)             // 30
#define E_TAIL    (N_E4 - E_ITERS * NTH)   // 135680
#define U_TAIL    (N_U4 - NTH)             // 137856

__device__ __forceinline__ float sq4(float4 v) {
    return v.x * v.x + v.y * v.y + v.z * v.z + v.w * v.w;
}

// ws layout: ws[2*b] = l2 partial, ws[2*b+1] = bce partial (plain stores, no init)
__global__ void __launch_bounds__(BLOCK, 4)
fused_kernel(const float4* __restrict__ ue4,
             const float4* __restrict__ ee4,
             const float4* __restrict__ re4,
             const float*  __restrict__ W,      // [D][D]
             const float4* __restrict__ b4,     // [D/4]
             const float*  __restrict__ labels,
             const int*    __restrict__ uidx,
             const int*    __restrict__ iidx,
             const int4*   __restrict__ adjE4,  // [N_ENTITY][2] int4
             const int4*   __restrict__ adjR4,
             float* __restrict__ ws) {
    // transposed W in LDS: sWT[j*16+i] = W[i][j], so column j is contiguous
    __shared__ float sWT[DIM * DIM];
    __shared__ float4 sb4[DIM / 4];
    if (threadIdx.x < DIM * DIM)
        sWT[threadIdx.x] = W[(threadIdx.x & 15) * DIM + (threadIdx.x >> 4)];
    if (threadIdx.x < DIM / 4) sb4[threadIdx.x] = b4[threadIdx.x];
    __syncthreads();

    const int lane4 = threadIdx.x & 3;   // dim-quad index (float4 of dims)
    const int rgrp  = threadIdx.x >> 2;  // row within block, 0..63
    const int row   = blockIdx.x * ROWS_PB + rgrp;
    const int tid_g = blockIdx.x * BLOCK + threadIdx.x;

    // ---- issue row-phase independent loads early (latency hides under stream)
    const int ui = uidx[row];
    const int it = iidx[row];
    const float4 u4  = ue4[ui * 4 + lane4];
    const float4 sv4 = ee4[it * 4 + lane4];
    const int4 a0 = adjE4[it * 2], a1 = adjE4[it * 2 + 1];
    const int4 r0 = adjR4[it * 2], r1 = adjR4[it * 2 + 1];

    // ---- streaming L2 sum-of-squares (compile-time unrolled, ~30 loads in flight)
    float l2 = 0.0f;
    {
        const float4* p = ee4 + tid_g;
        #pragma unroll
        for (int k = 0; k < E_ITERS; ++k) l2 += sq4(p[k * NTH]);
        if (tid_g < E_TAIL) l2 += sq4(p[E_ITERS * NTH]);
        l2 += sq4(ue4[tid_g]);
        if (tid_g < U_TAIL) l2 += sq4(ue4[tid_g + NTH]);
        if (tid_g < N_R4)   l2 += sq4(re4[tid_g]);
    }

    // ---- row phase: user-relation attention over 8 neighbors (4 lanes/row)
    const int ne[NNBR] = {a0.x, a0.y, a0.z, a0.w, a1.x, a1.y, a1.z, a1.w};
    const int nr[NNBR] = {r0.x, r0.y, r0.z, r0.w, r1.x, r1.y, r1.z, r1.w};

    float4 nv[NNBR];
    float sc[NNBR];
    #pragma unroll
    for (int k = 0; k < NNBR; ++k) {
        const float4 rv = re4[nr[k] * 4 + lane4];  // 64 relations -> cache-hot
        nv[k] = ee4[ne[k] * 4 + lane4];            // random gather, L3-hot after stream
        float s = u4.x * rv.x + u4.y * rv.y + u4.z * rv.z + u4.w * rv.w;
        s += __shfl_xor(s, 1, 4);
        s += __shfl_xor(s, 2, 4);
        sc[k] = s * (1.0f / 16.0f);
    }

    float m = sc[0];
    #pragma unroll
    for (int k = 1; k < NNBR; ++k) m = fmaxf(m, sc[k]);
    float e[NNBR], den = 0.0f;
    #pragma unroll
    for (int k = 0; k < NNBR; ++k) { e[k] = __expf(sc[k] - m); den += e[k]; }
    const float inv = 1.0f / den;

    float4 agg = make_float4(0.f, 0.f, 0.f, 0.f);
    #pragma unroll
    for (int k = 0; k < NNBR; ++k) {
        agg.x += e[k] * nv[k].x; agg.y += e[k] * nv[k].y;
        agg.z += e[k] * nv[k].z; agg.w += e[k] * nv[k].w;
    }

    float4 x4;
    x4.x = sv4.x + agg.x * inv; x4.y = sv4.y + agg.y * inv;
    x4.z = sv4.z + agg.z * inv; x4.w = sv4.w + agg.w * inv;

    // broadcast all 16 x_j across the 4-lane group
    float xall[DIM];
    #pragma unroll
    for (int src = 0; src < 4; ++src) {
        xall[4 * src + 0] = __shfl(x4.x, src, 4);
        xall[4 * src + 1] = __shfl(x4.y, src, 4);
        xall[4 * src + 2] = __shfl(x4.z, src, 4);
        xall[4 * src + 3] = __shfl(x4.w, src, 4);
    }

    // item[4*lane4 .. +3] = tanh(b + W x): use transposed-W columns (float4)
    const float4* sWT4 = (const float4*)sWT;
    float4 acc = sb4[lane4];
    #pragma unroll
    for (int j = 0; j < DIM; ++j) {
        const float4 wv = sWT4[j * 4 + lane4];
        acc.x += xall[j] * wv.x; acc.y += xall[j] * wv.y;
        acc.z += xall[j] * wv.z; acc.w += xall[j] * wv.w;
    }
    float4 item;
    item.x = tanhf(acc.x); item.y = tanhf(acc.y);
    item.z = tanhf(acc.z); item.w = tanhf(acc.w);

    float lg = u4.x * item.x + u4.y * item.y + u4.z * item.z + u4.w * item.w;
    lg += __shfl_xor(lg, 1, 4);
    lg += __shfl_xor(lg, 2, 4);

    float bce = 0.0f;
    if (lane4 == 0) {
        const float y = labels[row];
        bce = fmaxf(lg, 0.0f) - lg * y + log1pf(__expf(-fabsf(lg)));
    }

    // ---- block reduction of {l2, bce}
    #pragma unroll
    for (int o = 32; o > 0; o >>= 1) {
        bce += __shfl_down(bce, o);
        l2  += __shfl_down(l2, o);
    }
    __shared__ float sred[8];  // 4 waves x {l2, bce}
    const int wid = threadIdx.x >> 6;
    if ((threadIdx.x & 63) == 0) { sred[wid] = l2; sred[4 + wid] = bce; }
    __syncthreads();
    if (threadIdx.x == 0) {
        ws[2 * blockIdx.x]     = sred[0] + sred[1] + sred[2] + sred[3];
        ws[2 * blockIdx.x + 1] = sred[4] + sred[5] + sred[6] + sred[7];
    }
}

__global__ void __launch_bounds__(256)
finalize_kernel(const float* __restrict__ ws, float* __restrict__ out) {
    float l2 = 0.0f, bce = 0.0f;
    #pragma unroll
    for (int k = 0; k < GRID / 256; ++k) {
        const int i = threadIdx.x + k * 256;
        l2  += ws[2 * i];
        bce += ws[2 * i + 1];
    }
    #pragma unroll
    for (int o = 32; o > 0; o >>= 1) {
        l2  += __shfl_down(l2, o);
        bce += __shfl_down(bce, o);
    }
    __shared__ float sred[8];
    const int wid = threadIdx.x >> 6;
    if ((threadIdx.x & 63) == 0) { sred[wid] = l2; sred[4 + wid] = bce; }
    __syncthreads();
    if (threadIdx.x == 0) {
        const float l2t  = sred[0] + sred[1] + sred[2] + sred[3];
        const float bcet = sred[4] + sred[5] + sred[6] + sred[7];
        out[0] = bcet * (1.0f / (float)BATCH) + HALF_L2W * l2t;
    }
}

extern "C" void kernel_launch(void* const* d_in, const int* in_sizes, int n_in,
                              void* d_out, int out_size, void* d_ws, size_t ws_size,
                              hipStream_t stream) {
    const float* user_emb     = (const float*)d_in[0];
    const float* entity_emb   = (const float*)d_in[1];
    const float* relation_emb = (const float*)d_in[2];
    const float* agg_W        = (const float*)d_in[3];
    const float* agg_b        = (const float*)d_in[4];
    const float* labels       = (const float*)d_in[5];
    const int*   user_indices = (const int*)d_in[6];
    const int*   item_indices = (const int*)d_in[7];
    const int*   adj_entity   = (const int*)d_in[8];
    const int*   adj_relation = (const int*)d_in[9];

    float* ws  = (float*)d_ws;
    float* out = (float*)d_out;

    fused_kernel<<<GRID, BLOCK, 0, stream>>>(
        (const float4*)user_emb, (const float4*)entity_emb, (const float4*)relation_emb,
        agg_W, (const float4*)agg_b, labels,
        user_indices, item_indices,
        (const int4*)adj_entity, (const int4*)adj_relation, ws);

    finalize_kernel<<<1, 256, 0, stream>>>(ws, out);
}

// Round 4
// 42.870 us; speedup vs baseline: 1.1538x; 1.1538x over previous
//
#include <hip/hip_runtime.h>
#include <math.h>

// Problem constants (compile-time; from reference setup_inputs)
#define BATCH     65536
#define NNBR      8
#define DIM       16
#define HALF_L2W  5.0e-5f            // 0.5 * L2_WEIGHT

#define BLOCK     256
#define GRID      2048               // 1024 stream blocks + 1024 row blocks, parity-interleaved
#define N_SBLK    1024
#define STH       (N_SBLK * BLOCK)   // 262144 streaming threads
#define ROWS_PB   64                 // rows per row-block (4 lanes/row)

// table sizes in float4 units
#define N_E4      8000000            // 2,000,000 * 16 / 4
#define N_U4      400000             // 100,000 * 16 / 4
#define N_R4      256                // 64 * 16 / 4

#define E_ITERS   (N_E4 / STH)             // 30
#define E_TAIL    (N_E4 - E_ITERS * STH)   // 135680
#define U_TAIL    (N_U4 - STH)             // 137856

__device__ __forceinline__ float sq4(float4 v) {
    return v.x * v.x + v.y * v.y + v.z * v.z + v.w * v.w;
}

// ws layout: ws[2*b] = l2 partial, ws[2*b+1] = bce partial (plain stores, no init)
__global__ void __launch_bounds__(BLOCK, 4)
fused_kernel(const float4* __restrict__ ue4,
             const float4* __restrict__ ee4,
             const float4* __restrict__ re4,
             const float*  __restrict__ W,      // [D][D]
             const float4* __restrict__ b4,     // [D/4]
             const float*  __restrict__ labels,
             const int*    __restrict__ uidx,
             const int*    __restrict__ iidx,
             const int4*   __restrict__ adjE4,  // [N_ENTITY][2] int4
             const int4*   __restrict__ adjR4,
             float* __restrict__ ws) {
    float l2 = 0.0f, bce = 0.0f;

    const int role = blockIdx.x & 1;     // 0 = stream, 1 = row (block-uniform)
    const int rid  = blockIdx.x >> 1;    // role-local block id, 0..1023

    if (role == 0) {
        // ---------------- streaming L2 sum-of-squares ----------------
        const int tid = rid * BLOCK + threadIdx.x;
        const float4* p = ee4 + tid;
        #pragma unroll
        for (int k = 0; k < E_ITERS; ++k) l2 += sq4(p[k * STH]);
        if (tid < E_TAIL) l2 += sq4(p[E_ITERS * STH]);
        l2 += sq4(ue4[tid]);
        if (tid < U_TAIL) l2 += sq4(ue4[tid + STH]);
        if (tid < N_R4)   l2 += sq4(re4[tid]);
    } else {
        // ---------------- KGCN row work: 4 lanes/row, 64 rows/block ----------------
        __shared__ float sWT[DIM * DIM];       // sWT[j*16+i] = W[i][j]
        __shared__ float4 sb4[DIM / 4];
        if (threadIdx.x < DIM * DIM)
            sWT[threadIdx.x] = W[(threadIdx.x & 15) * DIM + (threadIdx.x >> 4)];
        if (threadIdx.x < DIM / 4) sb4[threadIdx.x] = b4[threadIdx.x];
        __syncthreads();

        const int lane4 = threadIdx.x & 3;     // dim-quad index
        const int rgrp  = threadIdx.x >> 2;    // row within block
        const int row   = rid * ROWS_PB + rgrp;

        const int ui = uidx[row];
        const int it = iidx[row];
        const float4 u4  = ue4[ui * 4 + lane4];
        const float4 sv4 = ee4[it * 4 + lane4];
        const int4 a0 = adjE4[it * 2], a1 = adjE4[it * 2 + 1];
        const int4 r0 = adjR4[it * 2], r1 = adjR4[it * 2 + 1];

        const int ne[NNBR] = {a0.x, a0.y, a0.z, a0.w, a1.x, a1.y, a1.z, a1.w};
        const int nr[NNBR] = {r0.x, r0.y, r0.z, r0.w, r1.x, r1.y, r1.z, r1.w};

        float4 nv[NNBR];
        float sc[NNBR];
        #pragma unroll
        for (int k = 0; k < NNBR; ++k) {
            const float4 rv = re4[nr[k] * 4 + lane4];  // 64 relations -> cache-hot
            nv[k] = ee4[ne[k] * 4 + lane4];            // random gather
            float s = u4.x * rv.x + u4.y * rv.y + u4.z * rv.z + u4.w * rv.w;
            s += __shfl_xor(s, 1, 4);
            s += __shfl_xor(s, 2, 4);
            sc[k] = s * (1.0f / 16.0f);
        }

        float m = sc[0];
        #pragma unroll
        for (int k = 1; k < NNBR; ++k) m = fmaxf(m, sc[k]);
        float e[NNBR], den = 0.0f;
        #pragma unroll
        for (int k = 0; k < NNBR; ++k) { e[k] = __expf(sc[k] - m); den += e[k]; }
        const float inv = 1.0f / den;

        float4 agg = make_float4(0.f, 0.f, 0.f, 0.f);
        #pragma unroll
        for (int k = 0; k < NNBR; ++k) {
            agg.x += e[k] * nv[k].x; agg.y += e[k] * nv[k].y;
            agg.z += e[k] * nv[k].z; agg.w += e[k] * nv[k].w;
        }

        float4 x4;
        x4.x = sv4.x + agg.x * inv; x4.y = sv4.y + agg.y * inv;
        x4.z = sv4.z + agg.z * inv; x4.w = sv4.w + agg.w * inv;

        float xall[DIM];
        #pragma unroll
        for (int src = 0; src < 4; ++src) {
            xall[4 * src + 0] = __shfl(x4.x, src, 4);
            xall[4 * src + 1] = __shfl(x4.y, src, 4);
            xall[4 * src + 2] = __shfl(x4.z, src, 4);
            xall[4 * src + 3] = __shfl(x4.w, src, 4);
        }

        const float4* sWT4 = (const float4*)sWT;
        float4 acc = sb4[lane4];
        #pragma unroll
        for (int j = 0; j < DIM; ++j) {
            const float4 wv = sWT4[j * 4 + lane4];
            acc.x += xall[j] * wv.x; acc.y += xall[j] * wv.y;
            acc.z += xall[j] * wv.z; acc.w += xall[j] * wv.w;
        }
        float4 item;
        item.x = tanhf(acc.x); item.y = tanhf(acc.y);
        item.z = tanhf(acc.z); item.w = tanhf(acc.w);

        float lg = u4.x * item.x + u4.y * item.y + u4.z * item.z + u4.w * item.w;
        lg += __shfl_xor(lg, 1, 4);
        lg += __shfl_xor(lg, 2, 4);

        if (lane4 == 0) {
            const float y = labels[row];
            bce = fmaxf(lg, 0.0f) - lg * y + log1pf(__expf(-fabsf(lg)));
        }
    }

    // ---------------- block reduction of {l2, bce} ----------------
    #pragma unroll
    for (int o = 32; o > 0; o >>= 1) {
        bce += __shfl_down(bce, o);
        l2  += __shfl_down(l2, o);
    }
    __shared__ float sred[8];  // 4 waves x {l2, bce}
    const int wid = threadIdx.x >> 6;
    if ((threadIdx.x & 63) == 0) { sred[wid] = l2; sred[4 + wid] = bce; }
    __syncthreads();
    if (threadIdx.x == 0) {
        ws[2 * blockIdx.x]     = sred[0] + sred[1] + sred[2] + sred[3];
        ws[2 * blockIdx.x + 1] = sred[4] + sred[5] + sred[6] + sred[7];
    }
}

__global__ void __launch_bounds__(256)
finalize_kernel(const float* __restrict__ ws, float* __restrict__ out) {
    float l2 = 0.0f, bce = 0.0f;
    #pragma unroll
    for (int k = 0; k < GRID / 256; ++k) {
        const int i = threadIdx.x + k * 256;
        l2  += ws[2 * i];
        bce += ws[2 * i + 1];
    }
    #pragma unroll
    for (int o = 32; o > 0; o >>= 1) {
        l2  += __shfl_down(l2, o);
        bce += __shfl_down(bce, o);
    }
    __shared__ float sred[8];
    const int wid = threadIdx.x >> 6;
    if ((threadIdx.x & 63) == 0) { sred[wid] = l2; sred[4 + wid] = bce; }
    __syncthreads();
    if (threadIdx.x == 0) {
        const float l2t  = sred[0] + sred[1] + sred[2] + sred[3];
        const float bcet = sred[4] + sred[5] + sred[6] + sred[7];
        out[0] = bcet * (1.0f / (float)BATCH) + HALF_L2W * l2t;
    }
}

extern "C" void kernel_launch(void* const* d_in, const int* in_sizes, int n_in,
                              void* d_out, int out_size, void* d_ws, size_t ws_size,
                              hipStream_t stream) {
    const float* user_emb     = (const float*)d_in[0];
    const float* entity_emb   = (const float*)d_in[1];
    const float* relation_emb = (const float*)d_in[2];
    const float* agg_W        = (const float*)d_in[3];
    const float* agg_b        = (const float*)d_in[4];
    const float* labels       = (const float*)d_in[5];
    const int*   user_indices = (const int*)d_in[6];
    const int*   item_indices = (const int*)d_in[7];
    const int*   adj_entity   = (const int*)d_in[8];
    const int*   adj_relation = (const int*)d_in[9];

    float* ws  = (float*)d_ws;
    float* out = (float*)d_out;

    fused_kernel<<<GRID, BLOCK, 0, stream>>>(
        (const float4*)user_emb, (const float4*)entity_emb, (const float4*)relation_emb,
        agg_W, (const float4*)agg_b, labels,
        user_indices, item_indices,
        (const int4*)adj_entity, (const int4*)adj_relation, ws);

    finalize_kernel<<<1, 256, 0, stream>>>(ws, out);
}